// Round 19
// baseline (168.777 us; speedup 1.0000x reference)
//
#include <hip/hip_runtime.h>
#include <hip/hip_bf16.h>

#define NCLS 345
#define CPAD 384
#define DIM  512
#define BCAP 256

typedef float f32x4 __attribute__((ext_vector_type(4)));
typedef float f32x4u __attribute__((ext_vector_type(4), aligned(4)));
typedef short s16x8 __attribute__((ext_vector_type(8)));
typedef unsigned long long u64;

__device__ __forceinline__ short f2bf(float f) {
  union { float f; unsigned u; } v; v.f = f;
  unsigned r = v.u + 0x7fffu + ((v.u >> 16) & 1u);   // RNE
  return (short)(r >> 16);
}

// ---- Stage 1: one pass over N, bucket (ent_bits<<32)|idx per class ----
__global__ __launch_bounds__(256) void scan_classes(
    const float* __restrict__ ent, const int* __restrict__ y_hat,
    u64* __restrict__ bucket, int* __restrict__ cnt, int N)
{
  int i = blockIdx.x * 256 + threadIdx.x;
  if (i >= N) return;
  int c = y_hat[i];
  unsigned eb = __float_as_uint(ent[i]);
  u64 key = ((u64)eb << 32) | (unsigned)i;
  int p = atomicAdd(&cnt[c], 1);
  if (p < BCAP) bucket[(size_t)c * BCAP + p] = key;
}

// ---- Stage 2: per-class select + normalized-row sum, emit FRAGMENT-PACKED W ----
// Packed: frag(kt 0..15, ct 0..23) of 1024B; lane = fq*16+fr holds
// W[col = ct*16+fr][k = kt*32+fq*8+j], j=0..7.
__global__ __launch_bounds__(512) void select_accum(
    const float* __restrict__ supports, const u64* __restrict__ bucket,
    const int* __restrict__ cnt, const int* __restrict__ fKp,
    short* __restrict__ Wp)
{
  const int c = blockIdx.x;
  const int tid = threadIdx.x;
  const int lane = tid & 63, w = tid >> 6;
  __shared__ u64   s_key[BCAP];
  __shared__ int   s_selidx[BCAP];
  __shared__ int   s_nsel;
  __shared__ float s_part[8][DIM];
  __shared__ float s_red[8];
  if (tid == 0) s_nsel = 0;
  const int S = (c < NCLS) ? min(cnt[c], BCAP) : 0;
  const int K = fKp[0];
  for (int e = tid; e < S; e += 512) s_key[e] = bucket[(size_t)c * BCAP + e];
  __syncthreads();
  for (int e = tid; e < S; e += 512) {
    u64 ke = s_key[e];
    int r = 0;
    for (int j = 0; j < S; ++j) r += (s_key[j] < ke) ? 1 : 0;
    if (r < K) { int p = atomicAdd(&s_nsel, 1); s_selidx[p] = (int)(unsigned)(ke & 0xffffffffull); }
  }
  __syncthreads();
  const int nsel = s_nsel;
  f32x4 p0 = {0.f,0.f,0.f,0.f}, p1 = {0.f,0.f,0.f,0.f};
  for (int e0 = w; e0 < nsel; e0 += 16) {
    const int e1 = e0 + 8;
    const bool h1 = (e1 < nsel);
    const f32x4* r0 = (const f32x4*)(supports + (size_t)s_selidx[e0] * DIM);
    f32x4 a0 = r0[lane], a1 = r0[lane + 64];
    f32x4 b0 = {0.f,0.f,0.f,0.f}, b1 = {0.f,0.f,0.f,0.f};
    if (h1) {
      const f32x4* r1 = (const f32x4*)(supports + (size_t)s_selidx[e1] * DIM);
      b0 = r1[lane]; b1 = r1[lane + 64];
    }
    float s0 = 0.f, s1 = 0.f;
#pragma unroll
    for (int j = 0; j < 4; ++j) {
      s0 = fmaf(a0[j], a0[j], s0); s0 = fmaf(a1[j], a1[j], s0);
      s1 = fmaf(b0[j], b0[j], s1); s1 = fmaf(b1[j], b1[j], s1);
    }
#pragma unroll
    for (int off = 32; off; off >>= 1) { s0 += __shfl_xor(s0, off); s1 += __shfl_xor(s1, off); }
    float c0 = 1.f / fmaxf(sqrtf(s0), 1e-12f);
    float c1 = 1.f / fmaxf(sqrtf(s1), 1e-12f);
#pragma unroll
    for (int j = 0; j < 4; ++j) { p0[j] = fmaf(a0[j], c0, p0[j]); p1[j] = fmaf(a1[j], c0, p1[j]); }
    if (h1) {
#pragma unroll
      for (int j = 0; j < 4; ++j) { p0[j] = fmaf(b0[j], c1, p0[j]); p1[j] = fmaf(b1[j], c1, p1[j]); }
    }
  }
  *(f32x4*)&s_part[w][lane * 4]       = p0;
  *(f32x4*)&s_part[w][256 + lane * 4] = p1;
  __syncthreads();
  float acc = 0.f;
#pragma unroll
  for (int ww = 0; ww < 8; ++ww) acc += s_part[ww][tid];
  float sq = acc * acc;
#pragma unroll
  for (int off = 32; off; off >>= 1) sq += __shfl_xor(sq, off);
  if (lane == 0) s_red[w] = sq;
  __syncthreads();
  float tot = 0.f;
#pragma unroll
  for (int ww = 0; ww < 8; ++ww) tot += s_red[ww];
  float sc = 1.f / fmaxf(sqrtf(tot), 1e-12f);
  {
    const int k = tid;
    const int kt = k >> 5, fq = (k >> 3) & 3, j = k & 7;
    const int ct = c >> 4, fr = c & 15;
    const size_t pos = (size_t)(kt * 24 + ct) * 512 + fq * 128 + fr * 8 + j;
    Wp[pos] = f2bf(acc * sc);
  }
}

// ---- Kernel B: PERSISTENT pipelined GEMM. 256 blocks x 4 chunks of 64 rows.
// Double-buffered A LDS (2x64KB, R18 balanced frag-linear layout). Per chunk:
// issue next chunk's z loads EARLY -> compute 16 steps -> cvt+ds_write late
// (T14) -> direct NT stores from acc -> raw s_barrier + lgkmcnt(0) ONLY
// (NT stores drain under next chunk's compute; no vmcnt(0) drain anywhere).
__global__ __launch_bounds__(512, 1) void gemm_zw(
    const float* __restrict__ z, const short* __restrict__ Wp,
    float* __restrict__ out)
{
  __shared__ __align__(16) char lds[131072];     // 2 x 64KB A buffers
  const int tid  = threadIdx.x;
  const int lane = tid & 63;
  const int w    = tid >> 6;                     // wave 0..7 = 48-col group
  const int fr   = lane & 15, fq = lane >> 4;
  const int blk  = blockIdx.x;
  const int Rbase = blk * 256;                   // 4 consecutive 64-row chunks

  const int st  = lane >> 2, sfq = lane & 3;     // staging decomposition

#define STAGE_LOAD(BASE)                                                       \
  {                                                                            \
    _Pragma("unroll")                                                          \
    for (int i = 0; i < 8; ++i) {                                              \
      const int row = i * 8 + w;                                               \
      const char* src = (const char*)(z + (size_t)((BASE) + row) * DIM);       \
      sl0[i] = *(const f32x4*)(src + lane * 32);                               \
      sl1[i] = *(const f32x4*)(src + lane * 32 + 16);                          \
    }                                                                          \
  }
#define STAGE_WRITE(P)                                                         \
  {                                                                            \
    _Pragma("unroll")                                                          \
    for (int i = 0; i < 8; ++i) {                                              \
      const int row = i * 8 + w;                                               \
      s16x8 b;                                                                 \
      _Pragma("unroll")                                                        \
      for (int j = 0; j < 4; ++j) { b[j] = f2bf(sl0[i][j]); b[4 + j] = f2bf(sl1[i][j]); } \
      const int mt = row >> 4, fr16 = row & 15;                                \
      const unsigned slot = (unsigned)((sfq * 16 + fr16) ^ (st & 15));         \
      *(s16x8*)(lds + (P) * 65536 + (size_t)(mt * 16 + st) * 1024 + slot * 16) = b; \
    }                                                                          \
  }

  f32x4 sl0[8], sl1[8];
  // prologue: stage chunk 0 into buf 0
  STAGE_LOAD(Rbase);
  STAGE_WRITE(0);
  __syncthreads();

  const char* pb = (const char*)Wp + (size_t)w * 3 * 1024 + (size_t)lane * 16;

#pragma unroll 1
  for (int c = 0; c < 4; ++c) {
    const int p = c & 1;
    const int Mb = Rbase + c * 64;
    if (c < 3) STAGE_LOAD(Mb + 64);              // issue-early (T14)

    f32x4 acc[4][3];
#pragma unroll
    for (int mt = 0; mt < 4; ++mt)
#pragma unroll
      for (int nt = 0; nt < 3; ++nt) acc[mt][nt] = f32x4{0.f, 0.f, 0.f, 0.f};

    s16x8 Bbuf[4][3];
#pragma unroll
    for (int s = 0; s < 3; ++s)
#pragma unroll
      for (int nt = 0; nt < 3; ++nt)
        Bbuf[s][nt] = *(const s16x8*)(pb + (size_t)s * 24576 + nt * 1024);

    const char* pa = lds + p * 65536;
#pragma unroll
    for (int t = 0; t < 16; ++t) {
      if (t + 3 < 16) {
#pragma unroll
        for (int nt = 0; nt < 3; ++nt)
          Bbuf[(t + 3) & 3][nt] = *(const s16x8*)(pb + (size_t)(t + 3) * 24576 + nt * 1024);
      }
      const unsigned rslot = (unsigned)(((fq * 16 + fr) ^ (t & 15)) * 16);
      s16x8 af[4];
#pragma unroll
      for (int mt = 0; mt < 4; ++mt)
        af[mt] = *(const s16x8*)(pa + (size_t)(mt * 16 + t) * 1024 + rslot);
      __builtin_amdgcn_s_setprio(1);
#pragma unroll
      for (int nt = 0; nt < 3; ++nt)
#pragma unroll
        for (int mt = 0; mt < 4; ++mt)
          acc[mt][nt] = __builtin_amdgcn_mfma_f32_16x16x32_bf16(Bbuf[t & 3][nt], af[mt], acc[mt][nt], 0, 0, 0);
      __builtin_amdgcn_s_setprio(0);
    }

    if (c < 3) STAGE_WRITE(p ^ 1);               // write-late into other buffer

    // epilogue: direct NT stores from acc (no barrier after)
#pragma unroll
    for (int mt = 0; mt < 4; ++mt) {
      const int row = Mb + mt * 16 + fr;
      float* prow = out + (size_t)row * NCLS;
#pragma unroll
      for (int nt = 0; nt < 3; ++nt) {
        const int colb = w * 48 + nt * 16 + fq * 4;
        if (colb + 3 < NCLS) {
          __builtin_nontemporal_store(acc[mt][nt], (f32x4u*)(prow + colb));
        } else {
#pragma unroll
          for (int j = 0; j < 4; ++j)
            if (colb + j < NCLS) __builtin_nontemporal_store(acc[mt][nt][j], prow + colb + j);
        }
      }
    }

    if (c < 3) {
      // chunk boundary: only LDS ordering needed -> raw barrier, NO vmcnt drain
      asm volatile("s_waitcnt lgkmcnt(0)" ::: "memory");
      __builtin_amdgcn_sched_barrier(0);
      __builtin_amdgcn_s_barrier();
    }
  }
#undef STAGE_LOAD
#undef STAGE_WRITE
}

extern "C" void kernel_launch(void* const* d_in, const int* in_sizes, int n_in,
                              void* d_out, int out_size, void* d_ws, size_t ws_size,
                              hipStream_t stream) {
  const float* z        = (const float*)d_in[0];
  const float* supports = (const float*)d_in[1];
  const float* ent      = (const float*)d_in[2];
  const int*   y_hat    = (const int*)d_in[3];
  const int*   fK       = (const int*)d_in[4];
  float* out = (float*)d_out;
  short* Wp  = (short*)d_ws;           // fragment-packed W, 384 KB
  const int N = in_sizes[2];
  const int M = in_sizes[0] / DIM;

  const size_t offC = (size_t)CPAD * DIM * 2;          // 393216
  const size_t offB = offC + 2048;
  int* cnt    = (int*)((char*)d_ws + offC);
  u64* bucket = (u64*)((char*)d_ws + offB);
  hipMemsetAsync(cnt, 0, CPAD * sizeof(int), stream);
  scan_classes<<<dim3((N + 255) / 256), dim3(256), 0, stream>>>(ent, y_hat, bucket, cnt, N);
  select_accum<<<dim3(CPAD), dim3(512), 0, stream>>>(supports, bucket, cnt, fK, Wp);
  gemm_zw<<<dim3(M / 256), dim3(512), 0, stream>>>(z, Wp, out);
}

// Round 20
// 78.040 us; speedup vs baseline: 2.1627x; 2.1627x over previous
//
#include <hip/hip_runtime.h>
#include <hip/hip_bf16.h>

#define NCLS 345
#define CPAD 384
#define DIM  512
#define BCAP 256

typedef float f32x4 __attribute__((ext_vector_type(4)));
typedef short s16x8 __attribute__((ext_vector_type(8)));
typedef unsigned long long u64;

__device__ __forceinline__ short f2bf(float f) {
  union { float f; unsigned u; } v; v.f = f;
  unsigned r = v.u + 0x7fffu + ((v.u >> 16) & 1u);   // RNE
  return (short)(r >> 16);
}

// ---- Stage 1: one pass over N, bucket (ent_bits<<32)|idx per class ----
__global__ __launch_bounds__(256) void scan_classes(
    const float* __restrict__ ent, const int* __restrict__ y_hat,
    u64* __restrict__ bucket, int* __restrict__ cnt, int N)
{
  int i = blockIdx.x * 256 + threadIdx.x;
  if (i >= N) return;
  int c = y_hat[i];
  unsigned eb = __float_as_uint(ent[i]);
  u64 key = ((u64)eb << 32) | (unsigned)i;
  int p = atomicAdd(&cnt[c], 1);
  if (p < BCAP) bucket[(size_t)c * BCAP + p] = key;
}

// ---- Stage 2: per-class select + normalized-row sum, emit FRAGMENT-PACKED W ----
// Packed: frag(kt 0..15, ct 0..23) of 1024B; lane = fq*16+fr holds
// W[col = ct*16+fr][k = kt*32+fq*8+j], j=0..7.
__global__ __launch_bounds__(512) void select_accum(
    const float* __restrict__ supports, const u64* __restrict__ bucket,
    const int* __restrict__ cnt, const int* __restrict__ fKp,
    short* __restrict__ Wp)
{
  const int c = blockIdx.x;
  const int tid = threadIdx.x;
  const int lane = tid & 63, w = tid >> 6;
  __shared__ u64   s_key[BCAP];
  __shared__ int   s_selidx[BCAP];
  __shared__ int   s_nsel;
  __shared__ float s_part[8][DIM];
  __shared__ float s_red[8];
  if (tid == 0) s_nsel = 0;
  const int S = (c < NCLS) ? min(cnt[c], BCAP) : 0;
  const int K = fKp[0];
  for (int e = tid; e < S; e += 512) s_key[e] = bucket[(size_t)c * BCAP + e];
  __syncthreads();
  for (int e = tid; e < S; e += 512) {
    u64 ke = s_key[e];
    int r = 0;
    for (int j = 0; j < S; ++j) r += (s_key[j] < ke) ? 1 : 0;
    if (r < K) { int p = atomicAdd(&s_nsel, 1); s_selidx[p] = (int)(unsigned)(ke & 0xffffffffull); }
  }
  __syncthreads();
  const int nsel = s_nsel;
  f32x4 p0 = {0.f,0.f,0.f,0.f}, p1 = {0.f,0.f,0.f,0.f};
  for (int e0 = w; e0 < nsel; e0 += 16) {
    const int e1 = e0 + 8;
    const bool h1 = (e1 < nsel);
    const f32x4* r0 = (const f32x4*)(supports + (size_t)s_selidx[e0] * DIM);
    f32x4 a0 = r0[lane], a1 = r0[lane + 64];
    f32x4 b0 = {0.f,0.f,0.f,0.f}, b1 = {0.f,0.f,0.f,0.f};
    if (h1) {
      const f32x4* r1 = (const f32x4*)(supports + (size_t)s_selidx[e1] * DIM);
      b0 = r1[lane]; b1 = r1[lane + 64];
    }
    float s0 = 0.f, s1 = 0.f;
#pragma unroll
    for (int j = 0; j < 4; ++j) {
      s0 = fmaf(a0[j], a0[j], s0); s0 = fmaf(a1[j], a1[j], s0);
      s1 = fmaf(b0[j], b0[j], s1); s1 = fmaf(b1[j], b1[j], s1);
    }
#pragma unroll
    for (int off = 32; off; off >>= 1) { s0 += __shfl_xor(s0, off); s1 += __shfl_xor(s1, off); }
    float c0 = 1.f / fmaxf(sqrtf(s0), 1e-12f);
    float c1 = 1.f / fmaxf(sqrtf(s1), 1e-12f);
#pragma unroll
    for (int j = 0; j < 4; ++j) { p0[j] = fmaf(a0[j], c0, p0[j]); p1[j] = fmaf(a1[j], c0, p1[j]); }
    if (h1) {
#pragma unroll
      for (int j = 0; j < 4; ++j) { p0[j] = fmaf(b0[j], c1, p0[j]); p1[j] = fmaf(b1[j], c1, p1[j]); }
    }
  }
  *(f32x4*)&s_part[w][lane * 4]       = p0;
  *(f32x4*)&s_part[w][256 + lane * 4] = p1;
  __syncthreads();
  float acc = 0.f;
#pragma unroll
  for (int ww = 0; ww < 8; ++ww) acc += s_part[ww][tid];
  float sq = acc * acc;
#pragma unroll
  for (int off = 32; off; off >>= 1) sq += __shfl_xor(sq, off);
  if (lane == 0) s_red[w] = sq;
  __syncthreads();
  float tot = 0.f;
#pragma unroll
  for (int ww = 0; ww < 8; ++ww) tot += s_red[ww];
  float sc = 1.f / fmaxf(sqrtf(tot), 1e-12f);
  {
    const int k = tid;
    const int kt = k >> 5, fq = (k >> 3) & 3, j = k & 7;
    const int ct = c >> 4, fr = c & 15;
    const size_t pos = (size_t)(kt * 24 + ct) * 512 + fq * 128 + fr * 8 + j;
    Wp[pos] = f2bf(acc * sc);
  }
}

// ---- Kernel B: out[M,345] = z[M,512] @ W ----
// R18 structure; B loads are INLINE-ASM global_load_dwordx4 into 4 named
// register sets, depth-3 in flight (9 loads), counted s_waitcnt vmcnt(6/3/0)
// + sched_barrier(0) (rule #18). The compiler cannot sink asm issue points,
// so the prefetch pipeline is real for the first time (verify: VGPR_Count).
__global__ __launch_bounds__(512, 2) void gemm_zw(
    const float* __restrict__ z, const short* __restrict__ Wp,
    float* __restrict__ out)
{
  __shared__ __align__(16) char lds[65536];      // A frags: 64 x 1KB
  const int tid  = threadIdx.x;
  const int lane = tid & 63;
  const int w    = tid >> 6;                     // wave 0..7 = 48-col group
  const int fr   = lane & 15, fq = lane >> 4;
  const int Mbase = blockIdx.x * 64;

  // ---- stage A (R18 balanced frag-linear layout) ----
#pragma unroll
  for (int i = 0; i < 8; ++i) {
    const int row = i * 8 + w;
    const char* src = (const char*)(z + (size_t)(Mbase + row) * DIM);
    f32x4 u0 = *(const f32x4*)(src + lane * 32);
    f32x4 u1 = *(const f32x4*)(src + lane * 32 + 16);
    s16x8 b;
#pragma unroll
    for (int j = 0; j < 4; ++j) { b[j] = f2bf(u0[j]); b[4 + j] = f2bf(u1[j]); }
    const int t  = lane >> 2, sfq = lane & 3;
    const int mt = row >> 4,  fr16 = row & 15;
    const unsigned slot = (unsigned)((sfq * 16 + fr16) ^ (t & 15));
    *(s16x8*)(lds + (size_t)(mt * 16 + t) * 1024 + slot * 16) = b;
  }
  __syncthreads();                               // staging loads drained by here

  const char* pb = (const char*)Wp + (size_t)w * 3 * 1024 + (size_t)lane * 16;

  f32x4 acc[4][3];
#pragma unroll
  for (int mt = 0; mt < 4; ++mt)
#pragma unroll
    for (int nt = 0; nt < 3; ++nt) acc[mt][nt] = f32x4{0.f, 0.f, 0.f, 0.f};

  s16x8 B0a,B0b,B0c, B1a,B1b,B1c, B2a,B2b,B2c, B3a,B3b,B3c;

#define ISSUE_SET(Sa,Sb,Sc,T)                                                   \
  asm volatile("global_load_dwordx4 %0, %1, off"                                \
               : "=v"(Sa) : "v"(pb + (size_t)(T) * 24576));                     \
  asm volatile("global_load_dwordx4 %0, %1, off"                                \
               : "=v"(Sb) : "v"(pb + (size_t)(T) * 24576 + 1024));              \
  asm volatile("global_load_dwordx4 %0, %1, off"                                \
               : "=v"(Sc) : "v"(pb + (size_t)(T) * 24576 + 2048));

  ISSUE_SET(B0a,B0b,B0c, 0)
  ISSUE_SET(B1a,B1b,B1c, 1)
  ISSUE_SET(B2a,B2b,B2c, 2)

#define GSTEP(T, WN, Ca,Cb,Cc, Ia,Ib,Ic)                                        \
  {                                                                             \
    asm volatile("s_waitcnt vmcnt(" #WN ")");                                   \
    __builtin_amdgcn_sched_barrier(0);                                          \
    if ((T) + 3 < 16) { ISSUE_SET(Ia,Ib,Ic, (T) + 3) }                          \
    const unsigned rslot = (unsigned)((((fq) * 16 + (fr)) ^ ((T) & 15)) * 16);  \
    s16x8 af0 = *(const s16x8*)(lds + (size_t)( 0 + (T)) * 1024 + rslot);       \
    s16x8 af1 = *(const s16x8*)(lds + (size_t)(16 + (T)) * 1024 + rslot);       \
    s16x8 af2 = *(const s16x8*)(lds + (size_t)(32 + (T)) * 1024 + rslot);       \
    s16x8 af3 = *(const s16x8*)(lds + (size_t)(48 + (T)) * 1024 + rslot);       \
    __builtin_amdgcn_s_setprio(1);                                              \
    acc[0][0] = __builtin_amdgcn_mfma_f32_16x16x32_bf16(Ca, af0, acc[0][0],0,0,0); \
    acc[1][0] = __builtin_amdgcn_mfma_f32_16x16x32_bf16(Ca, af1, acc[1][0],0,0,0); \
    acc[2][0] = __builtin_amdgcn_mfma_f32_16x16x32_bf16(Ca, af2, acc[2][0],0,0,0); \
    acc[3][0] = __builtin_amdgcn_mfma_f32_16x16x32_bf16(Ca, af3, acc[3][0],0,0,0); \
    acc[0][1] = __builtin_amdgcn_mfma_f32_16x16x32_bf16(Cb, af0, acc[0][1],0,0,0); \
    acc[1][1] = __builtin_amdgcn_mfma_f32_16x16x32_bf16(Cb, af1, acc[1][1],0,0,0); \
    acc[2][1] = __builtin_amdgcn_mfma_f32_16x16x32_bf16(Cb, af2, acc[2][1],0,0,0); \
    acc[3][1] = __builtin_amdgcn_mfma_f32_16x16x32_bf16(Cb, af3, acc[3][1],0,0,0); \
    acc[0][2] = __builtin_amdgcn_mfma_f32_16x16x32_bf16(Cc, af0, acc[0][2],0,0,0); \
    acc[1][2] = __builtin_amdgcn_mfma_f32_16x16x32_bf16(Cc, af1, acc[1][2],0,0,0); \
    acc[2][2] = __builtin_amdgcn_mfma_f32_16x16x32_bf16(Cc, af2, acc[2][2],0,0,0); \
    acc[3][2] = __builtin_amdgcn_mfma_f32_16x16x32_bf16(Cc, af3, acc[3][2],0,0,0); \
    __builtin_amdgcn_s_setprio(0);                                              \
  }

  GSTEP( 0,6, B0a,B0b,B0c, B3a,B3b,B3c)
  GSTEP( 1,6, B1a,B1b,B1c, B0a,B0b,B0c)
  GSTEP( 2,6, B2a,B2b,B2c, B1a,B1b,B1c)
  GSTEP( 3,6, B3a,B3b,B3c, B2a,B2b,B2c)
  GSTEP( 4,6, B0a,B0b,B0c, B3a,B3b,B3c)
  GSTEP( 5,6, B1a,B1b,B1c, B0a,B0b,B0c)
  GSTEP( 6,6, B2a,B2b,B2c, B1a,B1b,B1c)
  GSTEP( 7,6, B3a,B3b,B3c, B2a,B2b,B2c)
  GSTEP( 8,6, B0a,B0b,B0c, B3a,B3b,B3c)
  GSTEP( 9,6, B1a,B1b,B1c, B0a,B0b,B0c)
  GSTEP(10,6, B2a,B2b,B2c, B1a,B1b,B1c)
  GSTEP(11,6, B3a,B3b,B3c, B2a,B2b,B2c)
  GSTEP(12,6, B0a,B0b,B0c, B3a,B3b,B3c)
  GSTEP(13,6, B1a,B1b,B1c, B0a,B0b,B0c)
  GSTEP(14,3, B2a,B2b,B2c, B1a,B1b,B1c)
  GSTEP(15,0, B3a,B3b,B3c, B2a,B2b,B2c)
#undef GSTEP
#undef ISSUE_SET

  // ---- epilogue: two 32-row halves through LDS C-blob; NT stores ----
#pragma unroll
  for (int h = 0; h < 2; ++h) {
    __syncthreads();                   // h=0: A reads done; h=1: copy done
#pragma unroll
    for (int ml = 0; ml < 2; ++ml) {
      const int mt = h * 2 + ml;
      const int rl = ml * 16 + fr;     // local row 0..31
#pragma unroll
      for (int nt = 0; nt < 3; ++nt) {
        const int colb = w * 48 + nt * 16 + fq * 4;
#pragma unroll
        for (int j = 0; j < 4; ++j) {
          const int col = colb + j;
          if (col < NCLS)
            *(float*)(lds + (((size_t)rl * NCLS + col) << 2)) = acc[mt][nt][j];
        }
      }
    }
    __syncthreads();
    // flat coalesced nontemporal copy: 32*345*4 = 44160 B = 2760 x 16B
    char* dst = (char*)(out + (size_t)(Mbase + h * 32) * NCLS);
    for (int c = tid; c < 2760; c += 512) {
      f32x4 v = *(const f32x4*)(lds + c * 16);
      __builtin_nontemporal_store(v, (f32x4*)(dst + c * 16));
    }
  }
}

extern "C" void kernel_launch(void* const* d_in, const int* in_sizes, int n_in,
                              void* d_out, int out_size, void* d_ws, size_t ws_size,
                              hipStream_t stream) {
  const float* z        = (const float*)d_in[0];
  const float* supports = (const float*)d_in[1];
  const float* ent      = (const float*)d_in[2];
  const int*   y_hat    = (const int*)d_in[3];
  const int*   fK       = (const int*)d_in[4];
  float* out = (float*)d_out;
  short* Wp  = (short*)d_ws;           // fragment-packed W, 384 KB
  const int N = in_sizes[2];
  const int M = in_sizes[0] / DIM;

  const size_t offC = (size_t)CPAD * DIM * 2;          // 393216
  const size_t offB = offC + 2048;
  int* cnt    = (int*)((char*)d_ws + offC);
  u64* bucket = (u64*)((char*)d_ws + offB);
  hipMemsetAsync(cnt, 0, CPAD * sizeof(int), stream);
  scan_classes<<<dim3((N + 255) / 256), dim3(256), 0, stream>>>(ent, y_hat, bucket, cnt, N);
  select_accum<<<dim3(CPAD), dim3(512), 0, stream>>>(supports, bucket, cnt, fK, Wp);
  gemm_zw<<<dim3(M / 64), dim3(512), 0, stream>>>(z, Wp, out);
}